// Round 14
// baseline (1506.236 us; speedup 1.0000x reference)
//
#include <hip/hip_runtime.h>
#include <hip/hip_bf16.h>
#include <stdint.h>

// ---------------------------------------------------------------------------
// BiLSTM classifier: V=50000 E=100 H=128 B=128 T=1024 C=2. f32 I/O.
// Round 26 = r25 (1384us) + three chain-latency slivers:
// (1) MFMA depth 4 -> 2: two independent 2-deep partial chains p0/p1, select
//     per-lane halves, then one f32x2 add (saves ~2 dependent MFMA latencies;
//     +16 VGPR, extra adds off-chain);
// (2) ah ds_reads issued FIRST in the step (xp unpack + prefetch addressing
//     moved after -> they hide under ds_read latency instead of delaying it);
// (3) sig_o = eo*rcp(1+eo) precomputed in parallel with the c-chain -> h-tail
//     drops one dependent mul.
// Ledger: only chain-shortening wins (r19/r20/r22/r25); instr cuts, setprio,
// occupancy, bank-perm, chain-merge all null/neg. Step ~1514 cyc; this
// targets ~100-150 of it. If flat -> structural floor, declare roofline.
// ---------------------------------------------------------------------------

typedef unsigned short u16;
typedef short bf16x8 __attribute__((ext_vector_type(8)));
typedef unsigned short ushort8v __attribute__((ext_vector_type(8)));
typedef float f32x4 __attribute__((ext_vector_type(4)));
typedef float f32x2 __attribute__((ext_vector_type(2)));

#define NB 128
#define NT 1024
#define NH 128
#define TC 128         // chunk length (steps)
#define NCHUNK (NT / TC)
#define SMEM_BYTES 82944   // 2x > 160KB -> max 1 block/CU (lstm CU isolation)

#define L2E  1.44269504088896f
#define L2E2 2.88539008177793f

__device__ __forceinline__ u16 f2bf(float f) {
  union { float f; unsigned int i; } v; v.f = f;
  unsigned int i = v.i;
  return (u16)((i + 0x7FFFu + ((i >> 16) & 1u)) >> 16);  // RNE
}

#if __has_builtin(__builtin_amdgcn_exp2f)
__device__ __forceinline__ float fast_exp2(float x) { return __builtin_amdgcn_exp2f(x); }
#else
__device__ __forceinline__ float fast_exp2(float x) { return exp2f(x); }
#endif
#if __has_builtin(__builtin_amdgcn_rcpf)
__device__ __forceinline__ float fast_rcp(float x) { return __builtin_amdgcn_rcpf(x); }
#else
__device__ __forceinline__ float fast_rcp(float x) { return 1.0f / x; }
#endif

// RNE f32x2 -> packed bf16 dword (low16 = lo, high16 = hi). Verified correct
// on gfx950 in r15/r25 passing runs.
__device__ __forceinline__ unsigned int cvt_pk_bf16(float lo, float hi) {
  unsigned int r;
  asm("v_cvt_pk_bf16_f32 %0, %1, %2" : "=v"(r) : "v"(lo), "v"(hi));
  return r;
}

// LDS-only waits: lgkmcnt(0), vmcnt/expcnt unconstrained (imm 0xc07f, gfx9).
__device__ __forceinline__ void sync_lds() {
  __builtin_amdgcn_s_waitcnt(0xc07f);
  __builtin_amdgcn_s_barrier();
}

// ---------------------------------------------------------------------------
// pad w_ih_l0 f32 [512,100] -> bf16 [2][512][128], rows scaled by gate factor
__global__ void padw_kernel(const float* __restrict__ w0, const float* __restrict__ w1,
                            u16* __restrict__ out) {
  int idx = blockIdx.x * 256 + threadIdx.x;  // 131072
  int d = idx >> 16;
  int n = (idx >> 7) & 511;
  int k = idx & 127;
  float sc = ((n >> 7) == 2) ? L2E2 : L2E;
  const float* w = d ? w1 : w0;
  out[idx] = (k < 100) ? f2bf(w[n * 100 + k] * sc) : (u16)0;
}

// fused f32->bf16 convert for 6 weight arrays, rows scaled by gate factor.
__global__ void cvt6_kernel(const float* s0, const float* s1, const float* s2,
                            const float* s3, const float* s4, const float* s5,
                            u16* d0, u16* d1, u16* d2, u16* d3, u16* d4, u16* d5,
                            int n0, int n1, int n2, int n3, int n4, int n5) {
  int y = blockIdx.y;
  const float* s; u16* d; int n; int gs;
  switch (y) {
    case 0: s = s0; d = d0; n = n0; gs = 14; break;
    case 1: s = s1; d = d1; n = n1; gs = 14; break;
    case 2: s = s2; d = d2; n = n2; gs = 14; break;
    case 3: s = s3; d = d3; n = n3; gs = 14; break;
    case 4: s = s4; d = d4; n = n4; gs = 15; break;
    default: s = s5; d = d5; n = n5; gs = 15; break;
  }
  int i = blockIdx.x * 256 + threadIdx.x;
  if (i < n) {
    float sc = (((i >> gs) & 3) == 2) ? L2E2 : L2E;
    d[i] = f2bf(s[i] * sc);
  }
}

// ---------------------------------------------------------------------------
// Fused kernel. Blocks 0..31: lstm chunk `lc` (8 batch rows each, 2 dirs x
// 16 wg). Blocks 32..1055: proj chunk `pc`.
// xpc layout: [dir*16+wg][sl][colgrp8][gate4][lane64-as-u32][rr2] u16
//             (8KB step tiles; one dword per lane per gate per step).
template <int PK, int LL>
__global__ __launch_bounds__(512, 2) void fused_chunk(
    int do_lstm, int lc, int pc,
    const float* __restrict__ Aemb, const u16* __restrict__ Ah,
    const int* __restrict__ X,
    const u16* __restrict__ W0, const u16* __restrict__ W1,   // [512][PK] bf16
    const float* __restrict__ bih0, const float* __restrict__ bhh0,
    const float* __restrict__ bih1, const float* __restrict__ bhh1,
    u16* __restrict__ xpc0, u16* __restrict__ xpc1,           // double buffer
    const u16* __restrict__ WHH0, const u16* __restrict__ WHH1,
    u16* __restrict__ OUT, float* __restrict__ FINALS,
    u16* __restrict__ HS, float* __restrict__ CS)
{
  // dynamic smem (82944B requested -> occupancy cap 1 block/CU):
  // proj uses As(18432)+Bs(18432)+toks(512)=37376; lstm hb [2][8*136]=4352B
  extern __shared__ __align__(16) unsigned char smem[];

  const int tid = threadIdx.x;
  const int lane = tid & 63, wv = tid >> 6;
  const int l15 = lane & 15, q = lane >> 4;

  if (blockIdx.x >= 32) {
    // ------------------------- proj part (8 waves, 64x32 wave tiles) -------
    constexpr int BK = 64;
    constexpr int LDA = 72;
    constexpr bool GATHER = (PK == 128);
    u16* As = (u16*)smem;
    u16* Bs = As + 128 * LDA;
    int* toks = (int*)(Bs + 128 * LDA);

    const int pb = blockIdx.x - 32;
    const int b = pb & 127;
    const int gate = (pb >> 7) & 3;
    const int nt0 = gate * 128;
    const int dir = pb >> 9;
    const u16* W = dir ? W1 : W0;
    u16* XPC = (pc & 1) ? xpc1 : xpc0;

    const int wr = wv >> 2, wc = wv & 3;   // 2 x 4 waves

    if (GATHER) {
      if (tid < 128) {
        int t = dir ? (NT - 1 - pc * TC - tid) : (pc * TC + tid);
        toks[tid] = X[b * NT + t];
      }
    }

    f32x4 acc[4][2];
#pragma unroll
    for (int a = 0; a < 4; a++)
#pragma unroll
      for (int bb = 0; bb < 2; bb++)
        acc[a][bb] = (f32x4){0.f, 0.f, 0.f, 0.f};

    const int srow = tid >> 3;        // 0..63
    const int sseg = (tid & 7) * 8;   // 0..56

    for (int k0 = 0; k0 < PK; k0 += BK) {
      __syncthreads();   // also covers toks on first iteration
#pragma unroll
      for (int p = 0; p < 2; p++) {
        int row = srow + p * 64;
        if (GATHER) {
          int tok = toks[row];
          const float* er = Aemb + (size_t)tok * 100;
          int kb = k0 + sseg;
          union { ushort8v v; u16 e[8]; } tu;
          if (kb + 8 <= 100) {
            f32x4 a0 = *(const f32x4*)&er[kb];
            f32x4 a1 = *(const f32x4*)&er[kb + 4];
#pragma unroll
            for (int j = 0; j < 4; j++) { tu.e[j] = f2bf(a0[j]); tu.e[4 + j] = f2bf(a1[j]); }
          } else {
#pragma unroll
            for (int j = 0; j < 8; j++) tu.e[j] = (kb + j < 100) ? f2bf(er[kb + j]) : (u16)0;
          }
          *(ushort8v*)&As[row * LDA + sseg] = tu.v;
        } else {
          int t = dir ? (NT - 1 - pc * TC - row) : (pc * TC + row);
          const u16* srcA = Ah + (size_t)(b * NT + t) * PK + k0 + sseg;
          *(ushort8v*)&As[row * LDA + sseg] = *(const ushort8v*)srcA;
        }
        const u16* srcB = W + (size_t)(nt0 + row) * PK + k0 + sseg;
        *(ushort8v*)&Bs[row * LDA + sseg] = *(const ushort8v*)srcB;
      }
      __syncthreads();
#pragma unroll
      for (int kk = 0; kk < BK; kk += 32) {
        bf16x8 af[4], bfr[2];
#pragma unroll
        for (int mt = 0; mt < 4; mt++)
          af[mt] = *(const bf16x8*)&As[(wr * 64 + mt * 16 + l15) * LDA + kk + q * 8];
#pragma unroll
        for (int nt = 0; nt < 2; nt++)
          bfr[nt] = *(const bf16x8*)&Bs[(wc * 32 + nt * 16 + l15) * LDA + kk + q * 8];
#pragma unroll
        for (int mt = 0; mt < 4; mt++)
#pragma unroll
          for (int nt = 0; nt < 2; nt++)
            acc[mt][nt] = __builtin_amdgcn_mfma_f32_16x16x32_bf16(af[mt], bfr[nt], acc[mt][nt], 0, 0, 0);
      }
    }

    const float* bih = dir ? bih1 : bih0;
    const float* bhh = dir ? bhh1 : bhh0;
    const float gsc = (gate == 2) ? L2E2 : L2E;
    // xpc dest for value (sl, row=b&7, gate, col):
    //   u16 off = sl*4096 + (col>>4)*512 + gate*128 + (col&15)*2
    //           + ((rb>>1)&1)*64 + ((rb>>2)&1)*32 + (rb&1)
    const int rb = b & 7;
    u16* xo = XPC + (size_t)(dir * 16 + (b >> 3)) * TC * 4096
                  + ((rb >> 1) & 1) * 64 + ((rb >> 2) & 1) * 32 + (rb & 1) + l15 * 2;
#pragma unroll
    for (int nt = 0; nt < 2; nt++) {
      int col = wc * 32 + nt * 16 + l15;          // within-gate col 0..127
      int n = nt0 + col;
      float bias = (bih[n] + bhh[n]) * gsc;
      int bnt = ((wc * 2 + nt) * 4 + gate) * 128;
#pragma unroll
      for (int mt = 0; mt < 4; mt++) {
        int slb = wr * 64 + mt * 16 + q * 4;   // step-local index base
#pragma unroll
        for (int r = 0; r < 4; r++)
          xo[(size_t)(slb + r) * 4096 + bnt] = f2bf(acc[mt][nt][r] + bias);
      }
    }
    return;
  }

  // -------------- lstm part (8 rows/WG, dup-READ reg-select remap) ---------
  if (!do_lstm) return;

  __builtin_amdgcn_s_setprio(3);

  const int wg = blockIdx.x & 15, dir = blockIdx.x >> 4;
  const int hc = 16 * wv + l15;
  const u16* XPC = (lc & 1) ? xpc1 : xpc0;

  // lane row ownership: rows {row0, row0+1}, col hc
  // q=0 -> {0,1}, q=1 -> {4,5}, q=2 -> {2,3}, q=3 -> {6,7}
  const int row0 = ((lane >> 4) & 1) * 4 + (lane >> 5) * 2;

  const u16* Wp = dir ? WHH1 : WHH0;
  bf16x8 wf[4][4];
#pragma unroll
  for (int gi = 0; gi < 4; gi++)
#pragma unroll
    for (int kt = 0; kt < 4; kt++)
      wf[gi][kt] = *(const bf16x8*)&Wp[(gi * 128 + hc) * 128 + kt * 32 + q * 8];

  u16* hb = (u16*)smem;   // [2][8*136] u16; A-rows 8..15 alias 0..7 via read addr

  const int g0 = (dir * 128 + wg * 8 + row0) * 128 + hc;  // HS/CS row0 slot
  f32x2 cst2;
  if (lc == 0) {
    for (int i = tid; i < 2 * 8 * 136; i += 512) hb[i] = 0;
    cst2 = (f32x2){0.f, 0.f};
  } else {
    // restore plane 0 rows 0..7 (each lane: its 2 rows at col hc)
    hb[row0 * 136 + hc] = HS[g0];
    hb[(row0 + 1) * 136 + hc] = HS[g0 + 128];
    cst2[0] = CS[g0];
    cst2[1] = CS[g0 + 128];
    // plane 1 needs no init: every step writes all 8 rows of the next plane
  }

  // xp lane base: one dword per gate per step at (colgrp=wv, gate, lane)
  const u16* xb = XPC + (size_t)(dir * 16 + wg) * TC * 4096 + wv * 512 + lane * 2;

#define LDXP(dst, s) do {                                        \
    const u16* nb_ = xb + (size_t)(s) * 4096;                    \
    _Pragma("unroll")                                            \
    for (int gi_ = 0; gi_ < 4; gi_++)                            \
      (dst)[gi_] = *(const unsigned int*)(nb_ + gi_ * 128);      \
  } while (0)

  // depth-3 prefetch: 4 rotating dword[4] buffers, static indexing
  unsigned int xp[4][4];
  LDXP(xp[0], 0);
  LDXP(xp[1], 1);
  LDXP(xp[2], 2);

  const int t0 = dir ? (NT - 1 - lc * TC) : (lc * TC);
  const int tstep = dir ? -256 : 256;
  u16* optr[2];
  if (LL == 0) {
#pragma unroll
    for (int rr = 0; rr < 2; rr++)
      optr[rr] = OUT + ((size_t)(wg * 8 + row0 + rr) * NT + t0) * 256 + dir * 128 + hc;
  }

  const f32x4 zero4 = {0.f, 0.f, 0.f, 0.f};
  const bool hi32 = (lane >= 32);
  const int arow = (l15 & 7) * 136;    // dup-read A-row base (rows mod 8)

  __syncthreads();

  int p = 0;
#pragma unroll 1
  for (int sl = 0; sl < TC; sl += 4) {
#pragma unroll
    for (int jj = 0; jj < 4; jj++) {
      const int scur = sl + jj;

      // ---- chain head FIRST: issue the A-fragment ds_reads immediately
      bf16x8 ah[4];
#pragma unroll
      for (int kt = 0; kt < 4; kt++)
        ah[kt] = *(const bf16x8*)&hb[p * 1088 + arow + kt * 32 + q * 8];

      // ---- off-chain work hides under ds_read latency: xp unpack + prefetch
      const unsigned int* xcur = xp[jj];
      f32x2 xv[4];
#pragma unroll
      for (int gi = 0; gi < 4; gi++) {
        union { unsigned int u; float f; } lo, hi;
        lo.u = xcur[gi] << 16;
        hi.u = xcur[gi] & 0xFFFF0000u;
        xv[gi][0] = lo.f; xv[gi][1] = hi.f;
      }
      {
        int sn = scur + 3; if (sn > TC - 1) sn = TC - 1;
        LDXP(xp[(jj + 3) & 3], sn);
      }

      // ---- MFMA: two independent 2-deep partial chains per gate
      f32x4 p0[4], p1[4];
#pragma unroll
      for (int gi = 0; gi < 4; gi++) {
        p0[gi] = __builtin_amdgcn_mfma_f32_16x16x32_bf16(ah[0], wf[gi][0], zero4, 0, 0, 0);
        p1[gi] = __builtin_amdgcn_mfma_f32_16x16x32_bf16(ah[2], wf[gi][2], zero4, 0, 0, 0);
        p0[gi] = __builtin_amdgcn_mfma_f32_16x16x32_bf16(ah[1], wf[gi][1], p0[gi], 0, 0, 0);
        p1[gi] = __builtin_amdgcn_mfma_f32_16x16x32_bf16(ah[3], wf[gi][3], p1[gi], 0, 0, 0);
      }

      // dup remap select on each partial, then one f32x2 add
      f32x2 ar[4];
#pragma unroll
      for (int gi = 0; gi < 4; gi++) {
        f32x2 a0, a1;
        a0[0] = hi32 ? p0[gi][2] : p0[gi][0];
        a0[1] = hi32 ? p0[gi][3] : p0[gi][1];
        a1[0] = hi32 ? p1[gi][2] : p1[gi][0];
        a1[1] = hi32 ? p1[gi][3] : p1[gi][1];
        ar[gi] = a0 + a1;
      }

      // packed gate math (rr = vector lane). Preacts pre-scaled by L2E/L2E2.
      f32x2 pi = ar[0] + xv[0];
      f32x2 pf = ar[1] + xv[1];
      f32x2 pg = ar[2] + xv[2];
      f32x2 po = ar[3] + xv[3];
      f32x2 ei, ef, eg, eo;
      ei[0] = fast_exp2(pi[0]); ei[1] = fast_exp2(pi[1]);
      ef[0] = fast_exp2(pf[0]); ef[1] = fast_exp2(pf[1]);
      eg[0] = fast_exp2(pg[0]); eg[1] = fast_exp2(pg[1]);
      eo[0] = fast_exp2(po[0]); eo[1] = fast_exp2(po[1]);
      // sig_o precomputed in parallel with the c chain (off critical path)
      f32x2 Oo = 1.f + eo;
      f32x2 rO; rO[0] = fast_rcp(Oo[0]); rO[1] = fast_rcp(Oo[1]);
      f32x2 sgo = eo * rO;
      f32x2 A  = 1.f + ef;
      f32x2 Bv = 1.f + ei;
      f32x2 Cg = 1.f + eg;
      f32x2 BC = Bv * Cg;
      f32x2 num = cst2 * ef * BC + ei * (eg - 1.f) * A;
      f32x2 den = A * BC;
      f32x2 rden; rden[0] = fast_rcp(den[0]); rden[1] = fast_rcp(den[1]);
      f32x2 cn = num * rden;
      cst2 = cn;
      f32x2 tc2 = L2E2 * cn;
      f32x2 ec; ec[0] = fast_exp2(tc2[0]); ec[1] = fast_exp2(tc2[1]);
      f32x2 em1 = ec - 1.f;
      f32x2 ep1 = 1.f + ec;
      f32x2 rt; rt[0] = fast_rcp(ep1[0]); rt[1] = fast_rcp(ep1[1]);
      f32x2 hv2 = sgo * (em1 * rt);

      // single-instruction RNE pack; low16 = row0, hi16 = row0+1
      unsigned int hw = cvt_pk_bf16(hv2[0], hv2[1]);
      u16 hbv0 = (u16)hw;
      u16 hbv1 = (u16)(hw >> 16);
      u16* hn = hb + (p ^ 1) * 1088;
      hn[row0 * 136 + hc] = hbv0;
      hn[(row0 + 1) * 136 + hc] = hbv1;
      if (LL == 0) {
        *optr[0] = hbv0; optr[0] += tstep;
        *optr[1] = hbv1; optr[1] += tstep;
      }
      if (scur == TC - 1) {
        HS[g0] = hbv0;
        HS[g0 + 128] = hbv1;
        CS[g0] = cst2[0];
        CS[g0 + 128] = cst2[1];
        if (LL == 1 && lc == NCHUNK - 1) {
          FINALS[(wg * 8 + row0) * 256 + dir * 128 + hc] = hv2[0];
          FINALS[(wg * 8 + row0 + 1) * 256 + dir * 128 + hc] = hv2[1];
        }
      }
      sync_lds();   // h-exchange: lgkmcnt(0)+barrier; VMEM stays in flight
      p ^= 1;
    }
  }
#undef LDXP
}

// ---------------------------------------------------------------------------
// fc: out[b][c] = finals[b][:] . fc_w[c][:] + fc_b[c]  (all f32)
__global__ void fc_kernel(const float* __restrict__ finals, const float* __restrict__ fcw,
                          const float* __restrict__ fcb, float* __restrict__ out) {
  int tid = threadIdx.x;  // 256 = 128 b x 2 c
  int b = tid >> 1, cc = tid & 1;
  float s = fcb[cc];
  for (int k = 0; k < 256; k++) s += finals[b * 256 + k] * fcw[cc * 256 + k];
  out[b * 2 + cc] = s;
}

// ---------------------------------------------------------------------------
extern "C" void kernel_launch(void* const* d_in, const int* in_sizes, int n_in,
                              void* d_out, int out_size, void* d_ws, size_t ws_size,
                              hipStream_t stream) {
  const int*   x        = (const int*)d_in[0];
  const float* emb      = (const float*)d_in[1];
  const float* w_ih_l0  = (const float*)d_in[2];
  const float* w_hh_l0  = (const float*)d_in[3];
  const float* b_ih_l0  = (const float*)d_in[4];
  const float* b_hh_l0  = (const float*)d_in[5];
  const float* w_ih_l0r = (const float*)d_in[6];
  const float* w_hh_l0r = (const float*)d_in[7];
  const float* b_ih_l0r = (const float*)d_in[8];
  const float* b_hh_l0r = (const float*)d_in[9];
  const float* w_ih_l1  = (const float*)d_in[10];
  const float* w_hh_l1  = (const float*)d_in[11];
  const float* b_ih_l1  = (const float*)d_in[12];
  const float* b_hh_l1  = (const float*)d_in[13];
  const float* w_ih_l1r = (const float*)d_in[14];
  const float* w_hh_l1r = (const float*)d_in[15];
  const float* b_ih_l1r = (const float*)d_in[16];
  const float* b_hh_l1r = (const float*)d_in[17];
  const float* fc_w     = (const float*)d_in[18];
  const float* fc_b     = (const float*)d_in[19];
  float* out = (float*)d_out;

  // workspace layout — total 135,856,128 B (r8-r25 footprint, proven)
  char* ws = (char*)d_ws;
  size_t off = 0;
  u16*   h1cat = (u16*)(ws + off);   off += 67108864;  // [NB*NT][256] bf16
  u16*   xpc0  = (u16*)(ws + off);   off += 33554432;  // xp double buffer 0
  u16*   xpc1  = (u16*)(ws + off);   off += 33554432;  // xp double buffer 1
  u16*   w0pad = (u16*)(ws + off);   off += 262144;    // [2][512][128] bf16 (scaled)
  u16*   wih1b = (u16*)(ws + off);   off += 524288;    // [2][512][256] bf16 (scaled)
  u16*   whhb  = (u16*)(ws + off);   off += 524288;    // [4][512][128] bf16 (scaled)
  u16*   hs    = (u16*)(ws + off);   off += 65536;     // [2][128][128] bf16
  float* cs    = (float*)(ws + off); off += 131072;    // [2][128][128] f32
  float* fin   = (float*)(ws + off); off += 131072;    // [128][256] f32
  if (ws_size < off) return;  // constant across calls -> same work every call

  hipLaunchKernelGGL(padw_kernel, dim3(512), dim3(256), 0, stream,
                     w_ih_l0, w_ih_l0r, w0pad);
  hipLaunchKernelGGL(cvt6_kernel, dim3(512, 6), dim3(256), 0, stream,
                     w_hh_l0, w_hh_l0r, w_hh_l1, w_hh_l1r, w_ih_l1, w_ih_l1r,
                     whhb, whhb + 65536, whhb + 131072, whhb + 196608,
                     wih1b, wih1b + 131072,
                     65536, 65536, 65536, 65536, 131072, 131072);

  // Layer 0: launch k does proj0(k) [k<8] fused with lstm0(k-1) [k>0]
  for (int k = 0; k <= NCHUNK; k++) {
    int do_proj = (k < NCHUNK);
    int do_lstm = (k > 0);
    hipLaunchKernelGGL((fused_chunk<128, 0>), dim3(do_proj ? 1056 : 32), dim3(512),
                       SMEM_BYTES, stream,
                       do_lstm, k - 1, k,
                       emb, (const u16*)nullptr, x, w0pad, w0pad + 65536,
                       b_ih_l0, b_hh_l0, b_ih_l0r, b_hh_l0r,
                       xpc0, xpc1, whhb, whhb + 65536,
                       h1cat, fin, hs, cs);
  }
  // Layer 1: same pattern, proj reads h1cat (complete after layer-0 phase)
  for (int k = 0; k <= NCHUNK; k++) {
    int do_proj = (k < NCHUNK);
    int do_lstm = (k > 0);
    hipLaunchKernelGGL((fused_chunk<256, 1>), dim3(do_proj ? 1056 : 32), dim3(512),
                       SMEM_BYTES, stream,
                       do_lstm, k - 1, k,
                       (const float*)nullptr, h1cat, (const int*)nullptr,
                       wih1b, wih1b + 131072,
                       b_ih_l1, b_hh_l1, b_ih_l1r, b_hh_l1r,
                       xpc0, xpc1, whhb + 131072, whhb + 196608,
                       h1cat, fin, hs, cs);
  }
  hipLaunchKernelGGL(fc_kernel, dim3(1), dim3(256), 0, stream, fin, fc_w, fc_b, out);
}

// Round 15
// 1383.646 us; speedup vs baseline: 1.0886x; 1.0886x over previous
//
#include <hip/hip_runtime.h>
#include <hip/hip_bf16.h>
#include <stdint.h>

// ---------------------------------------------------------------------------
// BiLSTM classifier: V=50000 E=100 H=128 B=128 T=1024 C=2. f32 I/O.
// Round 27 = r25 verbatim (best verified: 1384us total, 80.8us/dispatch).
// r26 (MFMA chain split + reorder) regressed -10%: the 4 gate accumulators
// were ALREADY independent chains (cross-gate ILP hid MFMA latency); the
// split only added VGPR pressure + on-chain VALU. Reverted.
// Ledger: wins = chain-shortening only (r19/r20 remap elim, r16 prefetch,
// r22 dup-read+vmcnt, r25 cvt_pk+isolation). Refuted: arbitration (r13/r21),
// instr throughput (r14), banks (r23), chain merge (r24), MFMA depth (r26).
// Step = ~1514 cyc latency-bound serial recurrence; counters: MfmaUtil 5.9%,
// VALUBusy 13%, HBM 18% -> no throughput resource near saturation.
// ---------------------------------------------------------------------------

typedef unsigned short u16;
typedef short bf16x8 __attribute__((ext_vector_type(8)));
typedef unsigned short ushort8v __attribute__((ext_vector_type(8)));
typedef float f32x4 __attribute__((ext_vector_type(4)));
typedef float f32x2 __attribute__((ext_vector_type(2)));

#define NB 128
#define NT 1024
#define NH 128
#define TC 128         // chunk length (steps)
#define NCHUNK (NT / TC)
#define SMEM_BYTES 82944   // 2x > 160KB -> max 1 block/CU (lstm CU isolation)

#define L2E  1.44269504088896f
#define L2E2 2.88539008177793f

__device__ __forceinline__ u16 f2bf(float f) {
  union { float f; unsigned int i; } v; v.f = f;
  unsigned int i = v.i;
  return (u16)((i + 0x7FFFu + ((i >> 16) & 1u)) >> 16);  // RNE
}

#if __has_builtin(__builtin_amdgcn_exp2f)
__device__ __forceinline__ float fast_exp2(float x) { return __builtin_amdgcn_exp2f(x); }
#else
__device__ __forceinline__ float fast_exp2(float x) { return exp2f(x); }
#endif
#if __has_builtin(__builtin_amdgcn_rcpf)
__device__ __forceinline__ float fast_rcp(float x) { return __builtin_amdgcn_rcpf(x); }
#else
__device__ __forceinline__ float fast_rcp(float x) { return 1.0f / x; }
#endif

// RNE f32x2 -> packed bf16 dword (low16 = lo, high16 = hi). Verified correct
// on gfx950 in r15/r25 passing runs.
__device__ __forceinline__ unsigned int cvt_pk_bf16(float lo, float hi) {
  unsigned int r;
  asm("v_cvt_pk_bf16_f32 %0, %1, %2" : "=v"(r) : "v"(lo), "v"(hi));
  return r;
}

// LDS-only waits: lgkmcnt(0), vmcnt/expcnt unconstrained (imm 0xc07f, gfx9).
__device__ __forceinline__ void sync_lds() {
  __builtin_amdgcn_s_waitcnt(0xc07f);
  __builtin_amdgcn_s_barrier();
}

// ---------------------------------------------------------------------------
// pad w_ih_l0 f32 [512,100] -> bf16 [2][512][128], rows scaled by gate factor
__global__ void padw_kernel(const float* __restrict__ w0, const float* __restrict__ w1,
                            u16* __restrict__ out) {
  int idx = blockIdx.x * 256 + threadIdx.x;  // 131072
  int d = idx >> 16;
  int n = (idx >> 7) & 511;
  int k = idx & 127;
  float sc = ((n >> 7) == 2) ? L2E2 : L2E;
  const float* w = d ? w1 : w0;
  out[idx] = (k < 100) ? f2bf(w[n * 100 + k] * sc) : (u16)0;
}

// fused f32->bf16 convert for 6 weight arrays, rows scaled by gate factor.
__global__ void cvt6_kernel(const float* s0, const float* s1, const float* s2,
                            const float* s3, const float* s4, const float* s5,
                            u16* d0, u16* d1, u16* d2, u16* d3, u16* d4, u16* d5,
                            int n0, int n1, int n2, int n3, int n4, int n5) {
  int y = blockIdx.y;
  const float* s; u16* d; int n; int gs;
  switch (y) {
    case 0: s = s0; d = d0; n = n0; gs = 14; break;
    case 1: s = s1; d = d1; n = n1; gs = 14; break;
    case 2: s = s2; d = d2; n = n2; gs = 14; break;
    case 3: s = s3; d = d3; n = n3; gs = 14; break;
    case 4: s = s4; d = d4; n = n4; gs = 15; break;
    default: s = s5; d = d5; n = n5; gs = 15; break;
  }
  int i = blockIdx.x * 256 + threadIdx.x;
  if (i < n) {
    float sc = (((i >> gs) & 3) == 2) ? L2E2 : L2E;
    d[i] = f2bf(s[i] * sc);
  }
}

// ---------------------------------------------------------------------------
// Fused kernel. Blocks 0..31: lstm chunk `lc` (8 batch rows each, 2 dirs x
// 16 wg). Blocks 32..1055: proj chunk `pc`.
// xpc layout: [dir*16+wg][sl][colgrp8][gate4][lane64-as-u32][rr2] u16
//             (8KB step tiles; one dword per lane per gate per step).
template <int PK, int LL>
__global__ __launch_bounds__(512, 2) void fused_chunk(
    int do_lstm, int lc, int pc,
    const float* __restrict__ Aemb, const u16* __restrict__ Ah,
    const int* __restrict__ X,
    const u16* __restrict__ W0, const u16* __restrict__ W1,   // [512][PK] bf16
    const float* __restrict__ bih0, const float* __restrict__ bhh0,
    const float* __restrict__ bih1, const float* __restrict__ bhh1,
    u16* __restrict__ xpc0, u16* __restrict__ xpc1,           // double buffer
    const u16* __restrict__ WHH0, const u16* __restrict__ WHH1,
    u16* __restrict__ OUT, float* __restrict__ FINALS,
    u16* __restrict__ HS, float* __restrict__ CS)
{
  // dynamic smem (82944B requested -> occupancy cap 1 block/CU):
  // proj uses As(18432)+Bs(18432)+toks(512)=37376; lstm hb [2][8*136]=4352B
  extern __shared__ __align__(16) unsigned char smem[];

  const int tid = threadIdx.x;
  const int lane = tid & 63, wv = tid >> 6;
  const int l15 = lane & 15, q = lane >> 4;

  if (blockIdx.x >= 32) {
    // ------------------------- proj part (8 waves, 64x32 wave tiles) -------
    constexpr int BK = 64;
    constexpr int LDA = 72;
    constexpr bool GATHER = (PK == 128);
    u16* As = (u16*)smem;
    u16* Bs = As + 128 * LDA;
    int* toks = (int*)(Bs + 128 * LDA);

    const int pb = blockIdx.x - 32;
    const int b = pb & 127;
    const int gate = (pb >> 7) & 3;
    const int nt0 = gate * 128;
    const int dir = pb >> 9;
    const u16* W = dir ? W1 : W0;
    u16* XPC = (pc & 1) ? xpc1 : xpc0;

    const int wr = wv >> 2, wc = wv & 3;   // 2 x 4 waves

    if (GATHER) {
      if (tid < 128) {
        int t = dir ? (NT - 1 - pc * TC - tid) : (pc * TC + tid);
        toks[tid] = X[b * NT + t];
      }
    }

    f32x4 acc[4][2];
#pragma unroll
    for (int a = 0; a < 4; a++)
#pragma unroll
      for (int bb = 0; bb < 2; bb++)
        acc[a][bb] = (f32x4){0.f, 0.f, 0.f, 0.f};

    const int srow = tid >> 3;        // 0..63
    const int sseg = (tid & 7) * 8;   // 0..56

    for (int k0 = 0; k0 < PK; k0 += BK) {
      __syncthreads();   // also covers toks on first iteration
#pragma unroll
      for (int p = 0; p < 2; p++) {
        int row = srow + p * 64;
        if (GATHER) {
          int tok = toks[row];
          const float* er = Aemb + (size_t)tok * 100;
          int kb = k0 + sseg;
          union { ushort8v v; u16 e[8]; } tu;
          if (kb + 8 <= 100) {
            f32x4 a0 = *(const f32x4*)&er[kb];
            f32x4 a1 = *(const f32x4*)&er[kb + 4];
#pragma unroll
            for (int j = 0; j < 4; j++) { tu.e[j] = f2bf(a0[j]); tu.e[4 + j] = f2bf(a1[j]); }
          } else {
#pragma unroll
            for (int j = 0; j < 8; j++) tu.e[j] = (kb + j < 100) ? f2bf(er[kb + j]) : (u16)0;
          }
          *(ushort8v*)&As[row * LDA + sseg] = tu.v;
        } else {
          int t = dir ? (NT - 1 - pc * TC - row) : (pc * TC + row);
          const u16* srcA = Ah + (size_t)(b * NT + t) * PK + k0 + sseg;
          *(ushort8v*)&As[row * LDA + sseg] = *(const ushort8v*)srcA;
        }
        const u16* srcB = W + (size_t)(nt0 + row) * PK + k0 + sseg;
        *(ushort8v*)&Bs[row * LDA + sseg] = *(const ushort8v*)srcB;
      }
      __syncthreads();
#pragma unroll
      for (int kk = 0; kk < BK; kk += 32) {
        bf16x8 af[4], bfr[2];
#pragma unroll
        for (int mt = 0; mt < 4; mt++)
          af[mt] = *(const bf16x8*)&As[(wr * 64 + mt * 16 + l15) * LDA + kk + q * 8];
#pragma unroll
        for (int nt = 0; nt < 2; nt++)
          bfr[nt] = *(const bf16x8*)&Bs[(wc * 32 + nt * 16 + l15) * LDA + kk + q * 8];
#pragma unroll
        for (int mt = 0; mt < 4; mt++)
#pragma unroll
          for (int nt = 0; nt < 2; nt++)
            acc[mt][nt] = __builtin_amdgcn_mfma_f32_16x16x32_bf16(af[mt], bfr[nt], acc[mt][nt], 0, 0, 0);
      }
    }

    const float* bih = dir ? bih1 : bih0;
    const float* bhh = dir ? bhh1 : bhh0;
    const float gsc = (gate == 2) ? L2E2 : L2E;
    // xpc dest for value (sl, row=b&7, gate, col):
    //   u16 off = sl*4096 + (col>>4)*512 + gate*128 + (col&15)*2
    //           + ((rb>>1)&1)*64 + ((rb>>2)&1)*32 + (rb&1)
    const int rb = b & 7;
    u16* xo = XPC + (size_t)(dir * 16 + (b >> 3)) * TC * 4096
                  + ((rb >> 1) & 1) * 64 + ((rb >> 2) & 1) * 32 + (rb & 1) + l15 * 2;
#pragma unroll
    for (int nt = 0; nt < 2; nt++) {
      int col = wc * 32 + nt * 16 + l15;          // within-gate col 0..127
      int n = nt0 + col;
      float bias = (bih[n] + bhh[n]) * gsc;
      int bnt = ((wc * 2 + nt) * 4 + gate) * 128;
#pragma unroll
      for (int mt = 0; mt < 4; mt++) {
        int slb = wr * 64 + mt * 16 + q * 4;   // step-local index base
#pragma unroll
        for (int r = 0; r < 4; r++)
          xo[(size_t)(slb + r) * 4096 + bnt] = f2bf(acc[mt][nt][r] + bias);
      }
    }
    return;
  }

  // -------------- lstm part (8 rows/WG, dup-READ reg-select remap) ---------
  if (!do_lstm) return;

  __builtin_amdgcn_s_setprio(3);

  const int wg = blockIdx.x & 15, dir = blockIdx.x >> 4;
  const int hc = 16 * wv + l15;
  const u16* XPC = (lc & 1) ? xpc1 : xpc0;

  // lane row ownership: rows {row0, row0+1}, col hc
  // q=0 -> {0,1}, q=1 -> {4,5}, q=2 -> {2,3}, q=3 -> {6,7}
  const int row0 = ((lane >> 4) & 1) * 4 + (lane >> 5) * 2;

  const u16* Wp = dir ? WHH1 : WHH0;
  bf16x8 wf[4][4];
#pragma unroll
  for (int gi = 0; gi < 4; gi++)
#pragma unroll
    for (int kt = 0; kt < 4; kt++)
      wf[gi][kt] = *(const bf16x8*)&Wp[(gi * 128 + hc) * 128 + kt * 32 + q * 8];

  u16* hb = (u16*)smem;   // [2][8*136] u16; A-rows 8..15 alias 0..7 via read addr

  const int g0 = (dir * 128 + wg * 8 + row0) * 128 + hc;  // HS/CS row0 slot
  f32x2 cst2;
  if (lc == 0) {
    for (int i = tid; i < 2 * 8 * 136; i += 512) hb[i] = 0;
    cst2 = (f32x2){0.f, 0.f};
  } else {
    // restore plane 0 rows 0..7 (each lane: its 2 rows at col hc)
    hb[row0 * 136 + hc] = HS[g0];
    hb[(row0 + 1) * 136 + hc] = HS[g0 + 128];
    cst2[0] = CS[g0];
    cst2[1] = CS[g0 + 128];
    // plane 1 needs no init: every step writes all 8 rows of the next plane
  }

  // xp lane base: one dword per gate per step at (colgrp=wv, gate, lane)
  const u16* xb = XPC + (size_t)(dir * 16 + wg) * TC * 4096 + wv * 512 + lane * 2;

#define LDXP(dst, s) do {                                        \
    const u16* nb_ = xb + (size_t)(s) * 4096;                    \
    _Pragma("unroll")                                            \
    for (int gi_ = 0; gi_ < 4; gi_++)                            \
      (dst)[gi_] = *(const unsigned int*)(nb_ + gi_ * 128);      \
  } while (0)

  // depth-3 prefetch: 4 rotating dword[4] buffers, static indexing
  unsigned int xp[4][4];
  LDXP(xp[0], 0);
  LDXP(xp[1], 1);
  LDXP(xp[2], 2);

  const int t0 = dir ? (NT - 1 - lc * TC) : (lc * TC);
  const int tstep = dir ? -256 : 256;
  u16* optr[2];
  if (LL == 0) {
#pragma unroll
    for (int rr = 0; rr < 2; rr++)
      optr[rr] = OUT + ((size_t)(wg * 8 + row0 + rr) * NT + t0) * 256 + dir * 128 + hc;
  }

  const f32x4 zero4 = {0.f, 0.f, 0.f, 0.f};
  const bool hi32 = (lane >= 32);
  const int arow = (l15 & 7) * 136;    // dup-read A-row base (rows mod 8)

  __syncthreads();

  int p = 0;
#pragma unroll 1
  for (int sl = 0; sl < TC; sl += 4) {
#pragma unroll
    for (int jj = 0; jj < 4; jj++) {
      const int scur = sl + jj;

      // ---- step top: consume xp (vmcnt wait lands HERE, loads 3 steps old)
      const unsigned int* xcur = xp[jj];
      f32x2 xv[4];
#pragma unroll
      for (int gi = 0; gi < 4; gi++) {
        union { unsigned int u; float f; } lo, hi;
        lo.u = xcur[gi] << 16;
        hi.u = xcur[gi] & 0xFFFF0000u;
        xv[gi][0] = lo.f; xv[gi][1] = hi.f;
      }
      // issue prefetch for step scur+3 (clamped; dead tail loads never read)
      {
        int sn = scur + 3; if (sn > TC - 1) sn = TC - 1;
        LDXP(xp[(jj + 3) & 3], sn);
      }

      // ---- A-fragment reads (rows mod 8: broadcast for upper half)
      bf16x8 ah[4];
#pragma unroll
      for (int kt = 0; kt < 4; kt++)
        ah[kt] = *(const bf16x8*)&hb[p * 1088 + arow + kt * 32 + q * 8];

      // MFMA with zero C-init (xp added after select)
      f32x4 acc[4];
#pragma unroll
      for (int gi = 0; gi < 4; gi++) {
        acc[gi] = __builtin_amdgcn_mfma_f32_16x16x32_bf16(ah[0], wf[gi][0], zero4, 0, 0, 0);
#pragma unroll
        for (int kt = 1; kt < 4; kt++)
          acc[gi] = __builtin_amdgcn_mfma_f32_16x16x32_bf16(ah[kt], wf[gi][kt], acc[gi], 0, 0, 0);
      }

      // dup remap: A rows 8..15 alias 0..7, so lane(l15,q) reg r = batch row
      // (4q+r) mod 8. row0={0,4,2,6}[q] -> regs {0,1} lanes<32, {2,3} lanes>=32.
      f32x2 ar[4];
#pragma unroll
      for (int gi = 0; gi < 4; gi++) {
        ar[gi][0] = hi32 ? acc[gi][2] : acc[gi][0];
        ar[gi][1] = hi32 ? acc[gi][3] : acc[gi][1];
      }

      // packed gate math (rr = vector lane). Preacts pre-scaled by L2E/L2E2.
      f32x2 pi = ar[0] + xv[0];
      f32x2 pf = ar[1] + xv[1];
      f32x2 pg = ar[2] + xv[2];
      f32x2 po = ar[3] + xv[3];
      f32x2 ei, ef, eg, eo;
      ei[0] = fast_exp2(pi[0]); ei[1] = fast_exp2(pi[1]);
      ef[0] = fast_exp2(pf[0]); ef[1] = fast_exp2(pf[1]);
      eg[0] = fast_exp2(pg[0]); eg[1] = fast_exp2(pg[1]);
      eo[0] = fast_exp2(po[0]); eo[1] = fast_exp2(po[1]);
      f32x2 A  = 1.f + ef;
      f32x2 Bv = 1.f + ei;
      f32x2 Cg = 1.f + eg;
      f32x2 BC = Bv * Cg;
      f32x2 num = cst2 * ef * BC + ei * (eg - 1.f) * A;
      f32x2 den = A * BC;
      f32x2 rden; rden[0] = fast_rcp(den[0]); rden[1] = fast_rcp(den[1]);
      f32x2 cn = num * rden;
      cst2 = cn;
      f32x2 tc2 = L2E2 * cn;
      f32x2 ec; ec[0] = fast_exp2(tc2[0]); ec[1] = fast_exp2(tc2[1]);
      f32x2 d2 = (1.f + eo) * (1.f + ec);
      f32x2 r2; r2[0] = fast_rcp(d2[0]); r2[1] = fast_rcp(d2[1]);
      f32x2 hv2 = eo * (ec - 1.f) * r2;

      // single-instruction RNE pack; low16 = row0, hi16 = row0+1
      unsigned int hw = cvt_pk_bf16(hv2[0], hv2[1]);
      u16 hbv0 = (u16)hw;
      u16 hbv1 = (u16)(hw >> 16);
      u16* hn = hb + (p ^ 1) * 1088;
      hn[row0 * 136 + hc] = hbv0;
      hn[(row0 + 1) * 136 + hc] = hbv1;
      if (LL == 0) {
        *optr[0] = hbv0; optr[0] += tstep;
        *optr[1] = hbv1; optr[1] += tstep;
      }
      if (scur == TC - 1) {
        HS[g0] = hbv0;
        HS[g0 + 128] = hbv1;
        CS[g0] = cst2[0];
        CS[g0 + 128] = cst2[1];
        if (LL == 1 && lc == NCHUNK - 1) {
          FINALS[(wg * 8 + row0) * 256 + dir * 128 + hc] = hv2[0];
          FINALS[(wg * 8 + row0 + 1) * 256 + dir * 128 + hc] = hv2[1];
        }
      }
      sync_lds();   // h-exchange: lgkmcnt(0)+barrier; VMEM stays in flight
      p ^= 1;
    }
  }
#undef LDXP
}

// ---------------------------------------------------------------------------
// fc: out[b][c] = finals[b][:] . fc_w[c][:] + fc_b[c]  (all f32)
__global__ void fc_kernel(const float* __restrict__ finals, const float* __restrict__ fcw,
                          const float* __restrict__ fcb, float* __restrict__ out) {
  int tid = threadIdx.x;  // 256 = 128 b x 2 c
  int b = tid >> 1, cc = tid & 1;
  float s = fcb[cc];
  for (int k = 0; k < 256; k++) s += finals[b * 256 + k] * fcw[cc * 256 + k];
  out[b * 2 + cc] = s;
}

// ---------------------------------------------------------------------------
extern "C" void kernel_launch(void* const* d_in, const int* in_sizes, int n_in,
                              void* d_out, int out_size, void* d_ws, size_t ws_size,
                              hipStream_t stream) {
  const int*   x        = (const int*)d_in[0];
  const float* emb      = (const float*)d_in[1];
  const float* w_ih_l0  = (const float*)d_in[2];
  const float* w_hh_l0  = (const float*)d_in[3];
  const float* b_ih_l0  = (const float*)d_in[4];
  const float* b_hh_l0  = (const float*)d_in[5];
  const float* w_ih_l0r = (const float*)d_in[6];
  const float* w_hh_l0r = (const float*)d_in[7];
  const float* b_ih_l0r = (const float*)d_in[8];
  const float* b_hh_l0r = (const float*)d_in[9];
  const float* w_ih_l1  = (const float*)d_in[10];
  const float* w_hh_l1  = (const float*)d_in[11];
  const float* b_ih_l1  = (const float*)d_in[12];
  const float* b_hh_l1  = (const float*)d_in[13];
  const float* w_ih_l1r = (const float*)d_in[14];
  const float* w_hh_l1r = (const float*)d_in[15];
  const float* b_ih_l1r = (const float*)d_in[16];
  const float* b_hh_l1r = (const float*)d_in[17];
  const float* fc_w     = (const float*)d_in[18];
  const float* fc_b     = (const float*)d_in[19];
  float* out = (float*)d_out;

  // workspace layout — total 135,856,128 B (r8-r25 footprint, proven)
  char* ws = (char*)d_ws;
  size_t off = 0;
  u16*   h1cat = (u16*)(ws + off);   off += 67108864;  // [NB*NT][256] bf16
  u16*   xpc0  = (u16*)(ws + off);   off += 33554432;  // xp double buffer 0
  u16*   xpc1  = (u16*)(ws + off);   off += 33554432;  // xp double buffer 1
  u16*   w0pad = (u16*)(ws + off);   off += 262144;    // [2][512][128] bf16 (scaled)
  u16*   wih1b = (u16*)(ws + off);   off += 524288;    // [2][512][256] bf16 (scaled)
  u16*   whhb  = (u16*)(ws + off);   off += 524288;    // [4][512][128] bf16 (scaled)
  u16*   hs    = (u16*)(ws + off);   off += 65536;     // [2][128][128] bf16
  float* cs    = (float*)(ws + off); off += 131072;    // [2][128][128] f32
  float* fin   = (float*)(ws + off); off += 131072;    // [128][256] f32
  if (ws_size < off) return;  // constant across calls -> same work every call

  hipLaunchKernelGGL(padw_kernel, dim3(512), dim3(256), 0, stream,
                     w_ih_l0, w_ih_l0r, w0pad);
  hipLaunchKernelGGL(cvt6_kernel, dim3(512, 6), dim3(256), 0, stream,
                     w_hh_l0, w_hh_l0r, w_hh_l1, w_hh_l1r, w_ih_l1, w_ih_l1r,
                     whhb, whhb + 65536, whhb + 131072, whhb + 196608,
                     wih1b, wih1b + 131072,
                     65536, 65536, 65536, 65536, 131072, 131072);

  // Layer 0: launch k does proj0(k) [k<8] fused with lstm0(k-1) [k>0]
  for (int k = 0; k <= NCHUNK; k++) {
    int do_proj = (k < NCHUNK);
    int do_lstm = (k > 0);
    hipLaunchKernelGGL((fused_chunk<128, 0>), dim3(do_proj ? 1056 : 32), dim3(512),
                       SMEM_BYTES, stream,
                       do_lstm, k - 1, k,
                       emb, (const u16*)nullptr, x, w0pad, w0pad + 65536,
                       b_ih_l0, b_hh_l0, b_ih_l0r, b_hh_l0r,
                       xpc0, xpc1, whhb, whhb + 65536,
                       h1cat, fin, hs, cs);
  }
  // Layer 1: same pattern, proj reads h1cat (complete after layer-0 phase)
  for (int k = 0; k <= NCHUNK; k++) {
    int do_proj = (k < NCHUNK);
    int do_lstm = (k > 0);
    hipLaunchKernelGGL((fused_chunk<256, 1>), dim3(do_proj ? 1056 : 32), dim3(512),
                       SMEM_BYTES, stream,
                       do_lstm, k - 1, k,
                       (const float*)nullptr, h1cat, (const int*)nullptr,
                       wih1b, wih1b + 131072,
                       b_ih_l1, b_hh_l1, b_ih_l1r, b_hh_l1r,
                       xpc0, xpc1, whhb + 131072, whhb + 196608,
                       h1cat, fin, hs, cs);
  }
  hipLaunchKernelGGL(fc_kernel, dim3(1), dim3(256), 0, stream, fin, fc_w, fc_b, out);
}